// Round 7
// baseline (280.880 us; speedup 1.0000x reference)
//
#include <hip/hip_runtime.h>

// RetrievalLoss: out[i] = -sum_k Q[i,k] * D[i,k]   (N=131072, D=256, fp32)
//
// Round 6 (resubmit; bench hit GPUAcquisitionTimeout, never ran):
// rounds 1/3/5 all compiled to ~1 outstanding load per wave
// (VGPR_Count 12/32/44 -- the compiler re-serialized every source-level
// batching attempt) -> 2.7 TB/s delivered, 100 us. Fix: inline-asm
// global_load_dwordx4 with hand-placed COUNTED s_waitcnt vmcnt(8)
// (T4 discipline; rule #18: sched_barrier(0) after every wait so the
// scheduler can't hoist consumers above it). 16 loads (256 B/thread)
// genuinely in flight; compiler cannot insert vmcnt(0).
//
// Dataflow: 4 threads per row, each streams a contiguous 256 B chunk of
// Q and D (offset: immediates off one base pointer per stream), private
// accumulation, 2 butterflies, lane(&3)==0 stores. No LDS, no merge tree.

typedef float f4 __attribute__((ext_vector_type(4)));

#define GLD(dst, ptr, OFFSTR)                                       \
  asm volatile("global_load_dwordx4 %0, %1, off offset:" OFFSTR     \
               : "=v"(dst)                                          \
               : "v"(ptr))

#define VWAIT(NSTR)                                                 \
  do {                                                              \
    asm volatile("s_waitcnt vmcnt(" NSTR ")" ::: "memory");         \
    __builtin_amdgcn_sched_barrier(0);                              \
  } while (0)

#define DOT4ACC(acc, a, b)                                          \
  acc += a.x * b.x + a.y * b.y + a.z * b.z + a.w * b.w

__global__ __launch_bounds__(256) void neg_rowdot_kernel(
    const float* __restrict__ q, const float* __restrict__ d,
    float* __restrict__ out) {
  const int tid = blockIdx.x * 256 + threadIdx.x;
  const int row = tid >> 2;    // 4 threads per row
  const int chunk = tid & 3;   // each owns 64 floats = 256 B

  const float* qp = q + ((size_t)row * 256 + chunk * 64);
  const float* dp = d + ((size_t)row * 256 + chunk * 64);

  f4 qv[16], dv[16];

  // Issue groups 0+1: 16 loads outstanding (256 B/thread, 16 KiB/wave).
  GLD(qv[0], qp, "0");    GLD(dv[0], dp, "0");
  GLD(qv[1], qp, "16");   GLD(dv[1], dp, "16");
  GLD(qv[2], qp, "32");   GLD(dv[2], dp, "32");
  GLD(qv[3], qp, "48");   GLD(dv[3], dp, "48");
  GLD(qv[4], qp, "64");   GLD(dv[4], dp, "64");
  GLD(qv[5], qp, "80");   GLD(dv[5], dp, "80");
  GLD(qv[6], qp, "96");   GLD(dv[6], dp, "96");
  GLD(qv[7], qp, "112");  GLD(dv[7], dp, "112");

  VWAIT("8");  // group 0 complete; group 1 still in flight
  float a0 = 0.f, a1 = 0.f, a2 = 0.f, a3 = 0.f;
  // Issue group 2 before consuming group 0 (keep 16 outstanding).
  GLD(qv[8], qp, "128");  GLD(dv[8], dp, "128");
  GLD(qv[9], qp, "144");  GLD(dv[9], dp, "144");
  GLD(qv[10], qp, "160"); GLD(dv[10], dp, "160");
  GLD(qv[11], qp, "176"); GLD(dv[11], dp, "176");
  DOT4ACC(a0, qv[0], dv[0]);
  DOT4ACC(a1, qv[1], dv[1]);
  DOT4ACC(a2, qv[2], dv[2]);
  DOT4ACC(a3, qv[3], dv[3]);

  VWAIT("8");  // group 1 complete; group 2 in flight
  GLD(qv[12], qp, "192"); GLD(dv[12], dp, "192");
  GLD(qv[13], qp, "208"); GLD(dv[13], dp, "208");
  GLD(qv[14], qp, "224"); GLD(dv[14], dp, "224");
  GLD(qv[15], qp, "240"); GLD(dv[15], dp, "240");
  DOT4ACC(a0, qv[4], dv[4]);
  DOT4ACC(a1, qv[5], dv[5]);
  DOT4ACC(a2, qv[6], dv[6]);
  DOT4ACC(a3, qv[7], dv[7]);

  VWAIT("8");  // group 2 complete; group 3 in flight
  DOT4ACC(a0, qv[8], dv[8]);
  DOT4ACC(a1, qv[9], dv[9]);
  DOT4ACC(a2, qv[10], dv[10]);
  DOT4ACC(a3, qv[11], dv[11]);

  VWAIT("0");  // group 3 complete
  DOT4ACC(a0, qv[12], dv[12]);
  DOT4ACC(a1, qv[13], dv[13]);
  DOT4ACC(a2, qv[14], dv[14]);
  DOT4ACC(a3, qv[15], dv[15]);

  float s = (a0 + a1) + (a2 + a3);
  // Reduce across the 4 threads sharing a row.
  s += __shfl_xor(s, 1, 64);
  s += __shfl_xor(s, 2, 64);
  if ((tid & 3) == 0) out[row] = -s;
}

extern "C" void kernel_launch(void* const* d_in, const int* in_sizes, int n_in,
                              void* d_out, int out_size, void* d_ws, size_t ws_size,
                              hipStream_t stream) {
  const float* q = reinterpret_cast<const float*>(d_in[0]);
  const float* d = reinterpret_cast<const float*>(d_in[1]);
  float* out = reinterpret_cast<float*>(d_out);

  // 131072 rows x 4 threads = 524288 threads = 2048 blocks x 256.
  neg_rowdot_kernel<<<2048, 256, 0, stream>>>(q, d, out);
}